// Round 1
// baseline (1184.582 us; speedup 1.0000x reference)
//
#include <hip/hip_runtime.h>
#include <hip/hip_bf16.h>

// TransformerSpatialAttention on MI355X (gfx950)
// B=8, C=192, H=W=256, WS=8 -> 8192 windows x 64 tokens x 192 ch, NH=8, HD=24.
//
// Key algebraic reduction: output = sigmoid(mean_c(xa @ w_proj + b_proj))
//   = sigmoid( xa . wbar + bbar ),  wbar[k] = mean_c w_proj[k][c].
// And  sum_d (P@V)[t][d] wbar[h*24+d] = (P @ vw)[t],  vw[t'] = sum_d V[t'][d] wbar[h*24+d].
// => V never stored; projection GEMM never run; softmax row-sums via ones-B MFMA.

typedef __attribute__((ext_vector_type(4))) float floatx4;
typedef __attribute__((ext_vector_type(8))) short short8;

#define SCALE_Q 0.20412414523193154f   // 24^-0.5
#define LN_EPS 1e-5f

// ---- LDS layout (bytes) ----
#define RXN 200      // xn row stride in bf16 (192 + 8 pad, keeps 16B align, stride%32w==4)
#define RQK 264      // q/k row stride in bf16 (8 heads * 32 padded + 8)
#define RPC 40       // p-chunk row stride in bf16 (32 + 8)
#define OFF_XN    0
#define OFF_Q     25600
#define OFF_K     59392
#define OFF_PC    93184     // 8 waves * 64*40*2 = 40960 ; also LN scratch union (4KB)
#define OFF_LOGIT 134144    // 64 f32
#define OFF_VW    134400    // 8*64 f32
#define LDS_BYTES 136448

__device__ __forceinline__ floatx4 mfma16(short8 a, short8 b, floatx4 c) {
  return __builtin_amdgcn_mfma_f32_16x16x32_bf16(a, b, c, 0, 0, 0);
}

// ---------------------------------------------------------------------------
// prep: pack w_qkv^T into per-fragment lane order (bf16) + wbar/bbar
// wfrag layout: [ntile j (36)][kstep s (6)][lane (64)][8 bf16]
//   element = w_qkv[32s + (lane>>4)*8 + i][16j + (lane&15)]
// ---------------------------------------------------------------------------
__global__ void prep_kernel(const float* __restrict__ w_qkv,
                            const float* __restrict__ w_proj,
                            const float* __restrict__ b_proj,
                            __hip_bfloat16* __restrict__ wfrag,
                            float* __restrict__ wbar) {
  int tid = blockIdx.x * 256 + threadIdx.x;
  if (tid < 36 * 6 * 64) {
    int j = tid / 384, rem = tid % 384, ksr = rem / 64, l = rem % 64;
    int n  = 16 * j + (l & 15);
    int k0 = 32 * ksr + (l >> 4) * 8;
#pragma unroll
    for (int i = 0; i < 8; ++i)
      wfrag[(size_t)tid * 8 + i] = __float2bfloat16(w_qkv[(k0 + i) * 576 + n]);
  }
  if (tid < 192) {
    float s = 0.f;
    for (int c = 0; c < 192; ++c) s += w_proj[tid * 192 + c];
    wbar[tid] = s * (1.f / 192.f);
  } else if (tid == 192) {
    float s = 0.f;
    for (int c = 0; c < 192; ++c) s += b_proj[c];
    wbar[192] = s * (1.f / 192.f);
  }
}

// ---------------------------------------------------------------------------
// main fused kernel: 256 blocks (b = blk%8 -> XCD-stable image, wh = blk/8),
// each block loops ww = 0..31. 512 threads = 8 waves; wave w owns head w.
// ---------------------------------------------------------------------------
__global__ __launch_bounds__(512, 2) void swin_kernel(
    const float* __restrict__ x,
    const float* __restrict__ gamma,
    const float* __restrict__ beta,
    const float* __restrict__ b_qkv,
    const __hip_bfloat16* __restrict__ wfrag,
    const float* __restrict__ wbar,
    float* __restrict__ out) {
  __shared__ __align__(16) char smem[LDS_BYTES];
  __hip_bfloat16* xn = (__hip_bfloat16*)(smem + OFF_XN);
  __hip_bfloat16* lq = (__hip_bfloat16*)(smem + OFF_Q);
  __hip_bfloat16* lk = (__hip_bfloat16*)(smem + OFF_K);
  float* logit = (float*)(smem + OFF_LOGIT);
  float* vwf   = (float*)(smem + OFF_VW);
  float2* scratch = (float2*)(smem + OFF_PC);   // LN partials (union with p-chunks)

  const int tid = threadIdx.x;
  const int w   = tid >> 6;
  const int l   = tid & 63;
  const int l15 = l & 15;
  const int lg  = l >> 4;
  __hip_bfloat16* pcw = (__hip_bfloat16*)(smem + OFF_PC + w * (64 * RPC * 2));
  const floatx4 fzero = {0.f, 0.f, 0.f, 0.f};

  // one-time init: zero q/k head-pad columns (d=24..31 per head), logit, vw
  for (int i = tid; i < 64 * 64; i += 512) {
    int rr = i >> 6, hc = i & 63;
    int hh = hc >> 3, dd = 24 + (hc & 7);
    lq[rr * RQK + hh * 32 + dd] = __float2bfloat16(0.f);
    lk[rr * RQK + hh * 32 + dd] = __float2bfloat16(0.f);
  }
  if (tid < 64) logit[tid] = 0.f;
  vwf[tid] = 0.f;
  __syncthreads();

  const int p  = blockIdx.x;
  const int bb = p & 7;        // image (== XCD under blockIdx%8 round-robin)
  const int wh = p >> 3;       // window row
  const int tr = l >> 3, tc = l & 7;   // lane <-> token (r,c) in 8x8 window
  const int c0 = w * 24;               // this wave's channel slice
  const float* xb = x + (size_t)bb * 192 * 65536 + (size_t)(wh * 8 + tr) * 256 + tc;

  float xr[24];
#pragma unroll
  for (int i = 0; i < 24; ++i) xr[i] = xb[(size_t)(c0 + i) * 65536];

#pragma unroll 1
  for (int it = 0; it < 32; ++it) {
    // ---------------- LayerNorm (lane = token, regs hold 24 channels) -------
    float s1 = 0.f, s2 = 0.f;
#pragma unroll
    for (int i = 0; i < 24; ++i) { s1 += xr[i]; s2 += xr[i] * xr[i]; }
    scratch[w * 64 + l] = make_float2(s1, s2);
    __syncthreads();                                           // (A)
    float ts = 0.f, tq = 0.f;
#pragma unroll
    for (int g = 0; g < 8; ++g) { float2 v = scratch[g * 64 + l]; ts += v.x; tq += v.y; }
    const float mu   = ts * (1.f / 192.f);
    const float rstd = rsqrtf(tq * (1.f / 192.f) - mu * mu + LN_EPS);
#pragma unroll
    for (int i = 0; i < 24; ++i) {
      float xv = (xr[i] - mu) * rstd * gamma[c0 + i] + beta[c0 + i];
      xn[l * RXN + c0 + i] = __float2bfloat16(xv);
    }
    __syncthreads();                                           // (B)

    // prefetch next window's x into regs (drains at barrier C, overlaps QKV)
    if (it < 31) {
#pragma unroll
      for (int i = 0; i < 24; ++i)
        xr[i] = xb[(size_t)(c0 + i) * 65536 + (it + 1) * 8];
    }

    // ---------------- QKV GEMM: xn(64x192) @ w_qkv(192x576) -----------------
    short8 af[4][6];   // A fragments cached in regs (96 VGPRs)
#pragma unroll
    for (int mi = 0; mi < 4; ++mi)
#pragma unroll
      for (int ks = 0; ks < 6; ++ks)
        af[mi][ks] = *(const short8*)&xn[(16 * mi + l15) * RXN + 32 * ks + lg * 8];

    for (int j = w; j < 36; j += 8) {          // n-tiles round-robin over waves
      floatx4 aa[4];
#pragma unroll
      for (int mi = 0; mi < 4; ++mi) aa[mi] = fzero;
      const short8* bp = (const short8*)wfrag + (size_t)(j * 384 + l);
#pragma unroll
      for (int ks = 0; ks < 6; ++ks) {
        short8 bf = bp[ks * 64];               // coalesced 1KB, L2-resident
#pragma unroll
        for (int mi = 0; mi < 4; ++mi) aa[mi] = mfma16(af[mi][ks], bf, aa[mi]);
      }
      const int n = 16 * j + l15;
      const float bias = b_qkv[n];
      if (j < 12) {                            // ---- Q (SCALE folded in) ----
        const int hh = n / 24, dd = n - hh * 24;
#pragma unroll
        for (int mi = 0; mi < 4; ++mi)
#pragma unroll
          for (int rg = 0; rg < 4; ++rg) {
            int t = 16 * mi + lg * 4 + rg;
            lq[t * RQK + hh * 32 + dd] = __float2bfloat16((aa[mi][rg] + bias) * SCALE_Q);
          }
      } else if (j < 24) {                     // ---- K ----
        const int cc = n - 192;
        const int hh = cc / 24, dd = cc - hh * 24;
#pragma unroll
        for (int mi = 0; mi < 4; ++mi)
#pragma unroll
          for (int rg = 0; rg < 4; ++rg) {
            int t = 16 * mi + lg * 4 + rg;
            lk[t * RQK + hh * 32 + dd] = __float2bfloat16(aa[mi][rg] + bias);
          }
      } else {                                 // ---- V: reduce straight to vw ----
        const int cc = n - 384;
        const int hh = cc / 24;                // head boundaries are 8-aligned (8|24)
        const float wbv = wbar[cc];
        float part[16];
#pragma unroll
        for (int mi = 0; mi < 4; ++mi)
#pragma unroll
          for (int rg = 0; rg < 4; ++rg)
            part[mi * 4 + rg] = (aa[mi][rg] + bias) * wbv;
#pragma unroll
        for (int v2 = 0; v2 < 16; ++v2) {      // head-pure 8-lane reduction
          float t0 = part[v2];
          t0 += __shfl_xor(t0, 1);
          t0 += __shfl_xor(t0, 2);
          t0 += __shfl_xor(t0, 4);
          part[v2] = t0;
        }
        if ((l15 & 7) == 0) {
#pragma unroll
          for (int mi = 0; mi < 4; ++mi)
#pragma unroll
            for (int rg = 0; rg < 4; ++rg) {
              int t = 16 * mi + lg * 4 + rg;
              atomicAdd(&vwf[hh * 64 + t], part[mi * 4 + rg]);
            }
        }
      }
    }
    __syncthreads();                                           // (C)

    // ---------------- attention: wave w = head w -----------------------------
    {
      const int hh = w;
      short8 qf[4], kf[4];
#pragma unroll
      for (int i = 0; i < 4; ++i) {
        qf[i] = *(const short8*)&lq[(16 * i + l15) * RQK + hh * 32 + lg * 8];
        kf[i] = *(const short8*)&lk[(16 * i + l15) * RQK + hh * 32 + lg * 8];
      }
      floatx4 sc[4][4];                        // S = q.k^T (scaled), then exp
#pragma unroll
      for (int i = 0; i < 4; ++i)
#pragma unroll
        for (int j2 = 0; j2 < 4; ++j2)
          sc[i][j2] = mfma16(qf[i], kf[j2], fzero);
#pragma unroll
      for (int i = 0; i < 4; ++i)
#pragma unroll
        for (int j2 = 0; j2 < 4; ++j2)
#pragma unroll
          for (int rg = 0; rg < 4; ++rg)
            sc[i][j2][rg] = exp2f(sc[i][j2][rg] * 1.44269504f);  // no max-sub: |s|<~40 safe in fp32

      short8 vwfrag[2], onesf;
#pragma unroll
      for (int q2 = 0; q2 < 8; ++q2) onesf[q2] = (short)0x3F80;  // bf16 1.0
#pragma unroll
      for (int kc = 0; kc < 2; ++kc)
#pragma unroll
        for (int q2 = 0; q2 < 8; ++q2) {
          __hip_bfloat16 hb = __float2bfloat16(vwf[hh * 64 + kc * 32 + lg * 8 + q2]);
          short sv; __builtin_memcpy(&sv, &hb, 2);
          vwfrag[kc][q2] = sv;
        }

      floatx4 cacc[4], racc[4];                // contrib & rowsum accumulators
#pragma unroll
      for (int i = 0; i < 4; ++i) { cacc[i] = fzero; racc[i] = fzero; }
#pragma unroll
      for (int kc = 0; kc < 2; ++kc) {         // K-chunks of 32 through wave-private pc
#pragma unroll
        for (int i = 0; i < 4; ++i)
#pragma unroll
          for (int jj = 0; jj < 2; ++jj)
#pragma unroll
            for (int rg = 0; rg < 4; ++rg) {
              int row = 16 * i + lg * 4 + rg;
              pcw[row * RPC + jj * 16 + l15] = __float2bfloat16(sc[i][kc * 2 + jj][rg]);
            }
#pragma unroll
        for (int i = 0; i < 4; ++i) {
          short8 pf = *(const short8*)&pcw[(16 * i + l15) * RPC + lg * 8];
          cacc[i] = mfma16(pf, vwfrag[kc], cacc[i]);   // P @ vw
          racc[i] = mfma16(pf, onesf, racc[i]);        // row sums
        }
      }
      if (l15 == 0) {
#pragma unroll
        for (int i = 0; i < 4; ++i)
#pragma unroll
          for (int rg = 0; rg < 4; ++rg) {
            int row = 16 * i + lg * 4 + rg;
            atomicAdd(&logit[row], cacc[i][rg] / racc[i][rg]);
          }
      }
    }
    __syncthreads();                                           // (D)

    // ---------------- epilogue ----------------------------------------------
    if (tid < 64) {
      float vL = logit[tid] + wbar[192];
      out[(size_t)bb * 65536 + (size_t)(wh * 8 + (tid >> 3)) * 256 + it * 8 + (tid & 7)]
          = 1.f / (1.f + __expf(-vL));
      logit[tid] = 0.f;
    }
    vwf[tid] = 0.f;   // next window's vw accumulators (barriers A/B fence this)
  }
}

// ---------------------------------------------------------------------------
extern "C" void kernel_launch(void* const* d_in, const int* in_sizes, int n_in,
                              void* d_out, int out_size, void* d_ws, size_t ws_size,
                              hipStream_t stream) {
  const float* x      = (const float*)d_in[0];
  const float* gamma  = (const float*)d_in[1];
  const float* beta   = (const float*)d_in[2];
  const float* w_qkv  = (const float*)d_in[3];
  const float* b_qkv  = (const float*)d_in[4];
  const float* w_proj = (const float*)d_in[5];
  const float* b_proj = (const float*)d_in[6];
  float* out = (float*)d_out;

  __hip_bfloat16* wfrag = (__hip_bfloat16*)d_ws;          // 221184 B
  float* wbar = (float*)((char*)d_ws + 221184);           // 193 f32 (wbar + bbar)

  prep_kernel<<<54, 256, 0, stream>>>(w_qkv, w_proj, b_proj, wfrag, wbar);
  swin_kernel<<<256, 512, 0, stream>>>(x, gamma, beta, b_qkv, wfrag, wbar, out);
}